// Round 13
// baseline (174.496 us; speedup 1.0000x reference)
//
#include <hip/hip_runtime.h>
#include <hip/hip_bf16.h>

#define IN_DIM 128
#define OUT_DIM 64
#define FLOG 7                     // fine bucket: 128 nodes
#define FNPB (1 << FLOG)
#define MAXFINE 1024               // fine bins supported (n_nodes <= 128K)
#define BB 128                     // build grid blocks (long bin runs)
#define BT 512                     // build threads/block
#define EPB 12544                  // max edges per build block (LDS sort buffer)
#define NGRP 8                     // XCD groups (blockIdx & 7 ~ XCD id)
#define CAP_G 512                  // slot capacity per (bin, group)
#define CAP (NGRP * CAP_G)         // total slot capacity per fine bucket (4096)
#define SPILL_MAX 65536            // slot-overflow spill list capacity
#define KFT 256                    // kF threads/block (half-bucket blocks)
#define HALF 64                    // nodes per kF block
#define SBUF_CAP 2048              // kF sbuf entries (32 sigma for half-bucket)

static inline size_t align_up(size_t v, size_t a) { return (v + a - 1) & ~(a - 1); }

__device__ __forceinline__ unsigned short f2bf(float f) {
    unsigned int x = __float_as_uint(f);
    unsigned int r = (x + 0x7fffu + ((x >> 16) & 1u)) >> 16;  // RTNE
    return (unsigned short)r;
}

typedef _Float16 half8 __attribute__((ext_vector_type(8)));
typedef float f32x4 __attribute__((ext_vector_type(4)));

// ---------------------------------------------------------------------------
// k_build_mm: FUSED build + matmul (block-role split).
//   blocks [0, BB):      TWO-PASS build with BLOCK-LOCAL COUNTING SORT.
//                        Round 12 theory: the old single-pass scatter issued
//                        64 scattered 4B stores per wave (random bins). Now:
//                        pass1 histogram -> block-wide shfl prefix scan ->
//                        one global atomic per (block,bin) reserves a ~12-
//                        edge run -> pass2 scatters edges bin-sorted into
//                        LDS -> write-out walks each bin run with a wave =
//                        contiguous coalesced stores. XCD-grouped sub-slots
//                        kept (round 5 WIN). No global deg atomics (round 4:
//                        2x loss).
//   blocks [BB, BB+mmb): h(bf16) = x @ W via f16 MFMA 16x16x32, UNSCALED.
// ---------------------------------------------------------------------------
__global__ void __launch_bounds__(BT, 2) k_build_mm(
    const int* __restrict__ row, const int* __restrict__ col,
    int* __restrict__ BinSize, unsigned int* __restrict__ EdgeBuf,
    uint2* __restrict__ spill, int* __restrict__ spillcur,
    const float* __restrict__ x, const float* __restrict__ W,
    unsigned short* __restrict__ h,
    int n_edges, int n_nodes, int nbf, int chunk, int mm_blocks) {
    __shared__ int hist[MAXFINE];       // 4 KB: per-bin counts
    __shared__ int cursor[MAXFINE];     // 4 KB: local scatter cursors
    __shared__ int gdelta[MAXFINE];     // 4 KB: global sub-slot base per bin
    __shared__ int wtot[8];
    __shared__ unsigned int sped[EPB];  // 49 KB: bin-sorted packed edges
    if ((int)blockIdx.x < BB) {
        // ---------------- build path ----------------
        int t = threadIdx.x;
        int g = blockIdx.x & (NGRP - 1);            // ~XCD id
        int start = blockIdx.x * chunk;
        int end = min(n_edges, start + chunk);
        int n = end - start;

        for (int i = t; i < MAXFINE; i += BT) hist[i] = 0;
        __syncthreads();

        // pass 1: bin histogram
        for (int i = t; i < n; i += BT) {
            int c = col[start + i];                  // coalesced
            atomicAdd(&hist[c >> FLOG], 1);
        }
        __syncthreads();

        // block-wide prefix scan over 1024 bins (2 bins/thread) + reserve
        {
            int b0 = 2 * t, b1 = 2 * t + 1;
            int c0 = hist[b0], c1 = hist[b1];
            int s = c0 + c1;
            int lane = t & 63, wv = t >> 6;
#pragma unroll
            for (int off = 1; off < 64; off <<= 1) {
                int y = __shfl_up(s, off, 64);
                if (lane >= off) s += y;
            }
            if (lane == 63) wtot[wv] = s;
            __syncthreads();
            int woff = 0;
            for (int w = 0; w < wv; ++w) woff += wtot[w];
            int incl = woff + s;                     // inclusive through b1
            int l1 = incl - c1;                      // local start of b1
            int l0 = l1 - c0;                        // local start of b0
            cursor[b0] = l0;
            cursor[b1] = l1;
            int g0 = c0 ? atomicAdd(&BinSize[g * nbf + b0], c0) : 0;
            int g1 = c1 ? atomicAdd(&BinSize[g * nbf + b1], c1) : 0;
            gdelta[b0] = g0;
            gdelta[b1] = g1;
        }
        __syncthreads();

        // pass 2: re-read edges, scatter bin-sorted into LDS
        for (int i = t; i < n; i += BT) {
            int r = row[start + i];
            int c = col[start + i];
            int bin = c >> FLOG;
            int p = atomicAdd(&cursor[bin], 1);
            sped[p] = ((unsigned int)r << FLOG) | (unsigned int)(c & (FNPB - 1));
        }
        __syncthreads();

        // write-out: one wave walks each bin's run -> coalesced stores
        {
            int lane = t & 63, wv = t >> 6;
            for (int b = wv; b < nbf; b += 8) {
                int cnt = hist[b];
                if (!cnt) continue;
                int lst = cursor[b] - cnt;           // cursor ended at lst+cnt
                int goff = gdelta[b];
                unsigned int* dst = EdgeBuf + (size_t)b * CAP + g * CAP_G;
                for (int k = lane; k < cnt; k += 64) {
                    unsigned int v = sped[lst + k];
                    int off = goff + k;
                    if (off < CAP_G) {
                        dst[off] = v;
                    } else {
                        int sp = atomicAdd(spillcur, 1);
                        if (sp < SPILL_MAX)
                            spill[sp] = make_uint2(
                                v >> FLOG,
                                ((unsigned int)b << FLOG) | (v & (FNPB - 1)));
                    }
                }
            }
        }
    } else {
        // ---------------- matmul path (one wave per 16-node tile) ----------
        const int lane = threadIdx.x & 63;
        const int m = lane & 15;
        const int q = lane >> 4;
        const int wv = threadIdx.x >> 6;
        const int wid0 = ((int)blockIdx.x - BB) * 8 + wv;
        const int nwaves = mm_blocks * 8;
        const int ntiles = (n_nodes + 15) >> 4;

        half8 bfrag[4][4];                       // W fragments hoisted once
#pragma unroll
        for (int kt = 0; kt < 4; ++kt) {
#pragma unroll
            for (int nt = 0; nt < 4; ++nt) {
                int k0 = kt * 32 + q * 8;
                int c = nt * 16 + m;
#pragma unroll
                for (int j = 0; j < 8; ++j)
                    bfrag[kt][nt][j] = (_Float16)W[(size_t)(k0 + j) * OUT_DIM + c];
            }
        }

        for (int wid = wid0; wid < ntiles; wid += nwaves) {
            const int nb = wid << 4;
            int arow = nb + m;
            if (arow >= n_nodes) arow = n_nodes - 1;
            const float* xr = x + (size_t)arow * IN_DIM;

            f32x4 acc[4];
#pragma unroll
            for (int nt = 0; nt < 4; ++nt) acc[nt] = (f32x4){0.f, 0.f, 0.f, 0.f};

#pragma unroll
            for (int kt = 0; kt < 4; ++kt) {
                const float4* xp = (const float4*)(xr + kt * 32 + q * 8);
                float4 lo = xp[0];
                float4 hi = xp[1];
                half8 afrag;
                afrag[0] = (_Float16)lo.x; afrag[1] = (_Float16)lo.y;
                afrag[2] = (_Float16)lo.z; afrag[3] = (_Float16)lo.w;
                afrag[4] = (_Float16)hi.x; afrag[5] = (_Float16)hi.y;
                afrag[6] = (_Float16)hi.z; afrag[7] = (_Float16)hi.w;
#pragma unroll
                for (int nt = 0; nt < 4; ++nt)
                    acc[nt] = __builtin_amdgcn_mfma_f32_16x16x32_f16(
                        afrag, bfrag[kt][nt], acc[nt], 0, 0, 0);
            }

#pragma unroll
            for (int r = 0; r < 4; ++r) {
                int node = nb + q * 4 + r;
                if (node < n_nodes) {
                    unsigned short* hp = h + (size_t)node * OUT_DIM + m;
#pragma unroll
                    for (int nt = 0; nt < 4; ++nt)
                        hp[nt * 16] = f2bf(acc[nt][r]);   // UNSCALED
                }
            }
        }
    }
}

// ---------------------------------------------------------------------------
// kD: per-bucket degree histogram from the 8 sub-slots (+spill filter).
// Writes dis AND the raw per-node counts cntg[bk][128] so kF can skip its
// own histogram pass.
// ---------------------------------------------------------------------------
__global__ void __launch_bounds__(256) kD_degree(
    const unsigned int* __restrict__ EdgeBuf, const int* __restrict__ BinSize,
    const uint2* __restrict__ spill, const int* __restrict__ spillcur,
    float* __restrict__ dis, int* __restrict__ cntg, int n_nodes, int nbf) {
    __shared__ int cnt[FNPB];
    int t = threadIdx.x;
    int b = blockIdx.x;
    if (t < FNPB) cnt[t] = 0;
    __syncthreads();
    for (int g = 0; g < NGRP; ++g) {
        int szg = min(BinSize[g * nbf + b], CAP_G);
        const unsigned int* sl = EdgeBuf + (size_t)b * CAP + g * CAP_G;
        for (int i = t; i < szg; i += 256)
            atomicAdd(&cnt[sl[i] & (FNPB - 1)], 1);
    }
    int sn = min(*spillcur, SPILL_MAX);          // usually 0
    for (int i = t; i < sn; i += 256) {
        uint2 e = spill[i];
        if ((int)(e.y >> FLOG) == b) atomicAdd(&cnt[e.y & (FNPB - 1)], 1);
    }
    __syncthreads();
    if (t < FNPB) {
        int d = cnt[t];
        cntg[(size_t)b * FNPB + t] = d;          // coalesced 512 B/block
        int node = (b << FLOG) + t;
        if (node < n_nodes)
            dis[node] = (d > 0) ? rsqrtf((float)d) : 0.0f;
    }
}

// ---------------------------------------------------------------------------
// kF: HALF-BUCKET sort+gather (round 12 structure; pinned at ~44.5us by the
// h-gather's L2/L3 random-access equilibrium -- three successive micro-opts
// were null, so left unchanged this round).
// ---------------------------------------------------------------------------
__global__ void __launch_bounds__(KFT) kF_sortagg(
    const unsigned int* __restrict__ EdgeBuf, const int* __restrict__ BinSize,
    const uint2* __restrict__ spill, const int* __restrict__ spillcur,
    const unsigned short* __restrict__ h, const float* __restrict__ dis,
    const int* __restrict__ cntg, const float* __restrict__ b,
    float* __restrict__ out, int* __restrict__ arena, int* __restrict__ arenacur,
    int n_nodes, int nbf) {
    __shared__ int cnt[HALF];
    __shared__ int seg[HALF];
    __shared__ int cursor[HALF];
    __shared__ int sbuf[SBUF_CAP];
    __shared__ int abase_sh;
    int t = threadIdx.x;
    int bk = blockIdx.x >> 1;
    int halfid = blockIdx.x & 1;
    int lo = halfid * HALF;                      // node-local range [lo, lo+64)
    int nb0 = (bk << FLOG) + lo;
    int sn = min(*spillcur, SPILL_MAX);          // usually 0

    // wave-0 shfl scan over this half's 64 per-node counts
    if (t < 64) {
        int c = cntg[(size_t)bk * FNPB + lo + t];
        int s = c;
#pragma unroll
        for (int off = 1; off < 64; off <<= 1) {
            int y = __shfl_up(s, off, 64);
            if (t >= off) s += y;
        }
        cnt[t] = c;
        seg[t] = s;              // inclusive prefix
        cursor[t] = s - c;       // exclusive prefix
    }
    __syncthreads();

    int ne = seg[HALF - 1];
    if (t == 0 && ne > SBUF_CAP) abase_sh = atomicAdd(arenacur, ne);
    __syncthreads();

    const int lane = t & 63;
    const int wv = t >> 6;                       // 4 waves
    const int quarter = lane >> 4;
    const int qlane = lane & 15;
    float4 bias = ((const float4*)b)[qlane];

    if (ne <= SBUF_CAP) {
        for (int g = 0; g < NGRP; ++g) {
            int szg = min(BinSize[g * nbf + bk], CAP_G);
            const unsigned int* sl = EdgeBuf + (size_t)bk * CAP + g * CAP_G;
            for (int i = t; i < szg; i += KFT) {
                unsigned int v = sl[i];
                int nlocal = (int)(v & (FNPB - 1)) - lo;
                if ((unsigned)nlocal < HALF) {
                    int p = atomicAdd(&cursor[nlocal], 1);
                    sbuf[p] = (int)(v >> FLOG);
                }
            }
        }
        for (int i = t; i < sn; i += KFT) {
            uint2 e = spill[i];
            if ((int)(e.y >> FLOG) == bk) {
                int nlocal = (int)(e.y & (FNPB - 1)) - lo;
                if ((unsigned)nlocal < HALF) {
                    int p = atomicAdd(&cursor[nlocal], 1);
                    sbuf[p] = (int)e.x;
                }
            }
        }
        __syncthreads();

        for (int nl = wv; nl < HALF; nl += 4) {
            int node = nb0 + nl;
            if (node >= n_nodes) break;
            int e_ = seg[nl];
            int dcount = cnt[nl];
            int s_ = e_ - dcount;
            float a0 = 0.f, a1 = 0.f, a2 = 0.f, a3 = 0.f;
            for (int j0 = s_; j0 < e_; j0 += 16) {
                int i0 = j0 + quarter;
                int i1 = i0 + 4;
                int i2 = i0 + 8;
                int i3 = i0 + 12;
                int r0 = sbuf[i0 < e_ ? i0 : s_];
                int r1 = sbuf[i1 < e_ ? i1 : s_];
                int r2 = sbuf[i2 < e_ ? i2 : s_];
                int r3 = sbuf[i3 < e_ ? i3 : s_];
                float d0 = dis[r0];
                float d1 = dis[r1];
                float d2 = dis[r2];
                float d3 = dis[r3];
                uint2 v0 = make_uint2(0u, 0u), v1 = v0, v2 = v0, v3 = v0;
                if (i0 < e_)
                    v0 = *(const uint2*)(h + (size_t)r0 * OUT_DIM + qlane * 4);
                if (i1 < e_)
                    v1 = *(const uint2*)(h + (size_t)r1 * OUT_DIM + qlane * 4);
                if (i2 < e_)
                    v2 = *(const uint2*)(h + (size_t)r2 * OUT_DIM + qlane * 4);
                if (i3 < e_)
                    v3 = *(const uint2*)(h + (size_t)r3 * OUT_DIM + qlane * 4);
                a0 = fmaf(__uint_as_float(v0.x << 16), d0, a0);
                a1 = fmaf(__uint_as_float(v0.x & 0xFFFF0000u), d0, a1);
                a2 = fmaf(__uint_as_float(v0.y << 16), d0, a2);
                a3 = fmaf(__uint_as_float(v0.y & 0xFFFF0000u), d0, a3);
                a0 = fmaf(__uint_as_float(v1.x << 16), d1, a0);
                a1 = fmaf(__uint_as_float(v1.x & 0xFFFF0000u), d1, a1);
                a2 = fmaf(__uint_as_float(v1.y << 16), d1, a2);
                a3 = fmaf(__uint_as_float(v1.y & 0xFFFF0000u), d1, a3);
                a0 = fmaf(__uint_as_float(v2.x << 16), d2, a0);
                a1 = fmaf(__uint_as_float(v2.x & 0xFFFF0000u), d2, a1);
                a2 = fmaf(__uint_as_float(v2.y << 16), d2, a2);
                a3 = fmaf(__uint_as_float(v2.y & 0xFFFF0000u), d2, a3);
                a0 = fmaf(__uint_as_float(v3.x << 16), d3, a0);
                a1 = fmaf(__uint_as_float(v3.x & 0xFFFF0000u), d3, a1);
                a2 = fmaf(__uint_as_float(v3.y << 16), d3, a2);
                a3 = fmaf(__uint_as_float(v3.y & 0xFFFF0000u), d3, a3);
            }
            a0 += __shfl_xor(a0, 16, 64); a0 += __shfl_xor(a0, 32, 64);
            a1 += __shfl_xor(a1, 16, 64); a1 += __shfl_xor(a1, 32, 64);
            a2 += __shfl_xor(a2, 16, 64); a2 += __shfl_xor(a2, 32, 64);
            a3 += __shfl_xor(a3, 16, 64); a3 += __shfl_xor(a3, 32, 64);
            if (quarter == 0) {
                float dv = (dcount > 0) ? rsqrtf((float)dcount) : 0.0f;
                float4 o;
                o.x = fmaxf(fmaf(a0, dv, bias.x), 0.f);
                o.y = fmaxf(fmaf(a1, dv, bias.y), 0.f);
                o.z = fmaxf(fmaf(a2, dv, bias.z), 0.f);
                o.w = fmaxf(fmaf(a3, dv, bias.w), 0.f);
                ((float4*)(out + (size_t)node * OUT_DIM))[qlane] = o;
            }
        }
    } else {
        // impossible-size half-bucket: sort into a global arena slice
        int abase = abase_sh;
        for (int g = 0; g < NGRP; ++g) {
            int szg = min(BinSize[g * nbf + bk], CAP_G);
            const unsigned int* sl = EdgeBuf + (size_t)bk * CAP + g * CAP_G;
            for (int i = t; i < szg; i += KFT) {
                unsigned int v = sl[i];
                int nlocal = (int)(v & (FNPB - 1)) - lo;
                if ((unsigned)nlocal < HALF) {
                    int p = atomicAdd(&cursor[nlocal], 1);
                    arena[abase + p] = (int)(v >> FLOG);
                }
            }
        }
        for (int i = t; i < sn; i += KFT) {
            uint2 e = spill[i];
            if ((int)(e.y >> FLOG) == bk) {
                int nlocal = (int)(e.y & (FNPB - 1)) - lo;
                if ((unsigned)nlocal < HALF) {
                    int p = atomicAdd(&cursor[nlocal], 1);
                    arena[abase + p] = (int)e.x;
                }
            }
        }
        __threadfence();
        __syncthreads();
        for (int nl = wv; nl < HALF; nl += 4) {
            int node = nb0 + nl;
            if (node >= n_nodes) break;
            int e_ = seg[nl];
            int dcount = cnt[nl];
            int s_ = e_ - dcount;
            float a0 = 0.f, a1 = 0.f, a2 = 0.f, a3 = 0.f;
            for (int j0 = s_; j0 < e_; j0 += 8) {
                int iA = j0 + quarter;
                int iB = j0 + quarter + 4;
                int rA = arena[abase + (iA < e_ ? iA : s_)];
                int rB = arena[abase + (iB < e_ ? iB : s_)];
                float dA = dis[rA];
                float dB = dis[rB];
                uint2 vA = make_uint2(0u, 0u), vB = make_uint2(0u, 0u);
                if (iA < e_)
                    vA = *(const uint2*)(h + (size_t)rA * OUT_DIM + qlane * 4);
                if (iB < e_)
                    vB = *(const uint2*)(h + (size_t)rB * OUT_DIM + qlane * 4);
                a0 = fmaf(__uint_as_float(vA.x << 16), dA, a0);
                a1 = fmaf(__uint_as_float(vA.x & 0xFFFF0000u), dA, a1);
                a2 = fmaf(__uint_as_float(vA.y << 16), dA, a2);
                a3 = fmaf(__uint_as_float(vA.y & 0xFFFF0000u), dA, a3);
                a0 = fmaf(__uint_as_float(vB.x << 16), dB, a0);
                a1 = fmaf(__uint_as_float(vB.x & 0xFFFF0000u), dB, a1);
                a2 = fmaf(__uint_as_float(vB.y << 16), dB, a2);
                a3 = fmaf(__uint_as_float(vB.y & 0xFFFF0000u), dB, a3);
            }
            a0 += __shfl_xor(a0, 16, 64); a0 += __shfl_xor(a0, 32, 64);
            a1 += __shfl_xor(a1, 16, 64); a1 += __shfl_xor(a1, 32, 64);
            a2 += __shfl_xor(a2, 16, 64); a2 += __shfl_xor(a2, 32, 64);
            a3 += __shfl_xor(a3, 16, 64); a3 += __shfl_xor(a3, 32, 64);
            if (quarter == 0) {
                float dv = (dcount > 0) ? rsqrtf((float)dcount) : 0.0f;
                float4 o;
                o.x = fmaxf(fmaf(a0, dv, bias.x), 0.f);
                o.y = fmaxf(fmaf(a1, dv, bias.y), 0.f);
                o.z = fmaxf(fmaf(a2, dv, bias.z), 0.f);
                o.w = fmaxf(fmaf(a3, dv, bias.w), 0.f);
                ((float4*)(out + (size_t)node * OUT_DIM))[qlane] = o;
            }
        }
    }
}

// ---------------------------------------------------------------------------
// Last-resort fallback (exotic sizes): atomic scatter, fp32 h
// ---------------------------------------------------------------------------
#define MM_NODES 16
__global__ void __launch_bounds__(256) k_matmul_f32(
    const float* __restrict__ x, const float* __restrict__ W,
    const float* __restrict__ dis, float* __restrict__ h, int n_nodes) {
    __shared__ float xs[MM_NODES * IN_DIM];
    const int lane = threadIdx.x & 63;
    const int wv = threadIdx.x >> 6;
    float w[IN_DIM];
#pragma unroll
    for (int k = 0; k < IN_DIM; ++k) w[k] = W[k * OUT_DIM + lane];
    int nchunks = (n_nodes + MM_NODES - 1) / MM_NODES;
    for (int ch = blockIdx.x; ch < nchunks; ch += gridDim.x) {
        int base = ch * MM_NODES;
        int nrows = min(MM_NODES, n_nodes - base);
        __syncthreads();
        const float4* xg = (const float4*)(x + (size_t)base * IN_DIM);
        int nf4 = nrows * IN_DIM / 4;
        for (int i = threadIdx.x; i < nf4; i += 256) ((float4*)xs)[i] = xg[i];
        __syncthreads();
#pragma unroll
        for (int j = 0; j < 4; ++j) {
            int local = wv * 4 + j;
            int node = base + local;
            if (local < nrows) {
                const float4* xr = (const float4*)(xs + local * IN_DIM);
                float acc = 0.0f;
#pragma unroll
                for (int k4 = 0; k4 < IN_DIM / 4; ++k4) {
                    float4 xv = xr[k4];
                    acc = fmaf(xv.x, w[k4 * 4 + 0], acc);
                    acc = fmaf(xv.y, w[k4 * 4 + 1], acc);
                    acc = fmaf(xv.z, w[k4 * 4 + 2], acc);
                    acc = fmaf(xv.w, w[k4 * 4 + 3], acc);
                }
                h[(size_t)node * OUT_DIM + lane] = acc * dis[node];
            }
        }
    }
}

__global__ void k_degree_fb(const int* __restrict__ col, int* __restrict__ deg,
                            int n_edges) {
    int i = blockIdx.x * blockDim.x + threadIdx.x;
    int stride = gridDim.x * blockDim.x;
    for (; i < n_edges; i += stride) atomicAdd(&deg[col[i]], 1);
}

__global__ void k_rsqrt_fb(const int* __restrict__ deg, float* __restrict__ dis, int n) {
    int i = blockIdx.x * blockDim.x + threadIdx.x;
    if (i < n) {
        int d = deg[i];
        dis[i] = (d > 0) ? rsqrtf((float)d) : 0.0f;
    }
}

__global__ void __launch_bounds__(256) k_scatter_fb(
    const int* __restrict__ row, const int* __restrict__ col,
    const float* __restrict__ dis, const float* __restrict__ h,
    float* __restrict__ out, int n_edges) {
    const int lane = threadIdx.x & 63;
    int e = (blockIdx.x * blockDim.x + threadIdx.x) >> 6;
    int nw = (gridDim.x * blockDim.x) >> 6;
    for (; e < n_edges; e += nw) {
        int r = row[e];
        int c = col[e];
        float v = h[(size_t)r * OUT_DIM + lane] * dis[c];
        atomicAdd(&out[(size_t)c * OUT_DIM + lane], v);
    }
}

__global__ void k_bias_relu_fb(float* __restrict__ out, const float* __restrict__ b,
                               int total) {
    int i = blockIdx.x * blockDim.x + threadIdx.x;
    int stride = gridDim.x * blockDim.x;
    for (; i < total; i += stride) {
        float v = out[i] + b[i & (OUT_DIM - 1)];
        out[i] = fmaxf(v, 0.0f);
    }
}

extern "C" void kernel_launch(void* const* d_in, const int* in_sizes, int n_in,
                              void* d_out, int out_size, void* d_ws, size_t ws_size,
                              hipStream_t stream) {
    const float* x = (const float*)d_in[0];
    const int* ei = (const int*)d_in[1];  // [2, E] int32
    const float* W = (const float*)d_in[2];
    const float* b = (const float*)d_in[3];
    float* out = (float*)d_out;

    const int n_nodes = in_sizes[0] / IN_DIM;
    const int n_edges = in_sizes[1] / 2;
    const int* row = ei;
    const int* col = ei + n_edges;

    const int nbf = (n_nodes + FNPB - 1) >> FLOG;   // fine buckets
    const int chunk = (n_edges + BB - 1) / BB;

    // ---- workspace layout (BinSize[8][nbf] + cursors contiguous: one memset) ----
    char* wsb = (char*)d_ws;
    size_t off = 0;
    int* BinSize = (int*)(wsb + off);    off += (size_t)(nbf * NGRP + 8) * 4;
    int* spillcur = BinSize + nbf * NGRP;
    int* arenacur = BinSize + nbf * NGRP + 1;
    const size_t zero_bytes = off;
    off = align_up(off, 256);
    unsigned int* EdgeBuf = (unsigned int*)(wsb + off);
                                         off += align_up((size_t)nbf * CAP * 4, 256);
    uint2* spill = (uint2*)(wsb + off);  off += align_up((size_t)SPILL_MAX * 8, 256);
    int* arena = (int*)(wsb + off);      off += align_up((size_t)n_edges * 4, 256);
    float* dis = (float*)(wsb + off);    off += align_up((size_t)n_nodes * 4, 256);
    int* cntg = (int*)(wsb + off);       off += align_up((size_t)nbf * FNPB * 4, 256);
    unsigned short* h = (unsigned short*)(wsb + off);
                                         off += (size_t)n_nodes * OUT_DIM * 2;
    const size_t needed = off;

    const bool ok = (ws_size >= needed) && (nbf <= MAXFINE) &&
                    (chunk <= EPB) && (n_nodes <= (1 << 24));

    if (ok) {
        const int ntiles = (n_nodes + 15) >> 4;
        int mm_blocks = (ntiles + 15) / 16;          // 8 waves/block, 2 tiles/wave
        if (mm_blocks < 1) mm_blocks = 1;
        hipMemsetAsync(BinSize, 0, zero_bytes, stream);
        k_build_mm<<<BB + mm_blocks, BT, 0, stream>>>(
            row, col, BinSize, EdgeBuf, spill, spillcur,
            x, W, h, n_edges, n_nodes, nbf, chunk, mm_blocks);
        kD_degree<<<nbf, 256, 0, stream>>>(EdgeBuf, BinSize, spill, spillcur,
                                           dis, cntg, n_nodes, nbf);
        kF_sortagg<<<2 * nbf, KFT, 0, stream>>>(EdgeBuf, BinSize, spill, spillcur,
                                                h, dis, cntg, b, out, arena,
                                                arenacur, n_nodes, nbf);
    } else {
        // ---- last-resort fallback: atomic scatter, fp32 h ----
        char* p = (char*)d_ws;
        int* deg_f = (int*)p;
        float* dis_f = (float*)(p + align_up((size_t)n_nodes * 4, 256));
        float* h_f = (float*)(p + 2 * align_up((size_t)n_nodes * 4, 256));
        hipMemsetAsync(deg_f, 0, (size_t)n_nodes * 4, stream);
        hipMemsetAsync(out, 0, (size_t)out_size * 4, stream);
        k_degree_fb<<<1024, 256, 0, stream>>>(col, deg_f, n_edges);
        k_rsqrt_fb<<<(n_nodes + 255) / 256, 256, 0, stream>>>(deg_f, dis_f, n_nodes);
        k_matmul_f32<<<1024, 256, 0, stream>>>(x, W, dis_f, h_f, n_nodes);
        k_scatter_fb<<<2048, 256, 0, stream>>>(row, col, dis_f, h_f, out, n_edges);
        k_bias_relu_fb<<<2048, 256, 0, stream>>>(out, b, n_nodes * OUT_DIM);
    }
}

// Round 17
// 171.665 us; speedup vs baseline: 1.0165x; 1.0165x over previous
//
#include <hip/hip_runtime.h>
#include <hip/hip_bf16.h>

#define IN_DIM 128
#define OUT_DIM 64
#define FLOG 7                     // fine bucket: 128 nodes
#define FNPB (1 << FLOG)
#define MAXFINE 1024               // fine bins supported (n_nodes <= 128K)
#define BB 512                     // build grid blocks
#define BT 512                     // build threads/block
#define MAXE 8                     // edges staged in registers per thread
#define NGRP 8                     // XCD groups (blockIdx & 7 ~ XCD id)
#define CAP_G 512                  // slot capacity per (bin, group)
#define CAP (NGRP * CAP_G)         // total slot capacity per fine bucket (4096)
#define SPILL_MAX 65536            // slot-overflow spill list capacity
#define KFT 256                    // kF threads/block (half-bucket blocks)
#define HALF 64                    // nodes per kF block
#define SBUF_CAP 2048              // kF sbuf entries (32 sigma for half-bucket)

static inline size_t align_up(size_t v, size_t a) { return (v + a - 1) & ~(a - 1); }

__device__ __forceinline__ unsigned short f2bf(float f) {
    unsigned int x = __float_as_uint(f);
    unsigned int r = (x + 0x7fffu + ((x >> 16) & 1u)) >> 16;  // RTNE
    return (unsigned short)r;
}

typedef _Float16 half8 __attribute__((ext_vector_type(8)));
typedef float f32x4 __attribute__((ext_vector_type(4)));

// ---------------------------------------------------------------------------
// k_build_mm: FUSED build + matmul (block-role split). Round-12 form (best
// measured 172.6-172.8us, passed). Single-pass register-staged scatter with
// XCD-grouped sub-slots (round 5 WIN). No global deg atomics (round 4: 2x
// loss). Round 13 counting-sort reverted (LDS/occupancy loss). Round 16
// cooperative kD+kF fusion reverted (grid.sync broken under graph capture
// -> stale dis -> absmax 468).
// ---------------------------------------------------------------------------
__global__ void __launch_bounds__(BT, 4) k_build_mm(
    const int* __restrict__ row, const int* __restrict__ col,
    int* __restrict__ BinSize, unsigned int* __restrict__ EdgeBuf,
    uint2* __restrict__ spill, int* __restrict__ spillcur,
    const float* __restrict__ x, const float* __restrict__ W,
    unsigned short* __restrict__ h,
    int n_edges, int n_nodes, int nbf, int chunk, int mm_blocks) {
    if ((int)blockIdx.x < BB) {
        // ---------------- build path ----------------
        __shared__ int hist[MAXFINE];   // 4 KB: counts -> reserved base/cursor
        int t = threadIdx.x;
        int g = blockIdx.x & (NGRP - 1);            // ~XCD id
        int start = blockIdx.x * chunk;
        int end = min(n_edges, start + chunk);
        int n = end - start;

        for (int i = t; i < nbf; i += BT) hist[i] = 0;
        __syncthreads();

        int er[MAXE], ec[MAXE];
#pragma unroll
        for (int u = 0; u < MAXE; ++u) {
            int i = t + u * BT;                     // coalesced
            ec[u] = -1;
            if (i < n) {
                er[u] = row[start + i];
                int c = col[start + i];
                ec[u] = c;
                atomicAdd(&hist[c >> FLOG], 1);
            }
        }
        __syncthreads();
        // reserve sub-slot ranges: group-major BinSize[g*nbf+bin] keeps the
        // atomic's cache line private to this block-group's XCD
        for (int i = t; i < nbf; i += BT) {
            int cv = hist[i];
            hist[i] = cv ? atomicAdd(&BinSize[g * nbf + i], cv) : 0;
        }
        __syncthreads();
#pragma unroll
        for (int u = 0; u < MAXE; ++u) {            // scatter from registers
            int c = ec[u];
            if (c >= 0) {
                int bin = c >> FLOG;
                int pos = atomicAdd(&hist[bin], 1);
                if (pos < CAP_G) {
                    EdgeBuf[(size_t)bin * CAP + g * CAP_G + pos] =
                        ((unsigned int)er[u] << FLOG) | (unsigned int)(c & (FNPB - 1));
                } else {
                    int sp = atomicAdd(spillcur, 1);
                    if (sp < SPILL_MAX)
                        spill[sp] = make_uint2((unsigned int)er[u], (unsigned int)c);
                }
            }
        }
    } else {
        // ---------------- matmul path (one wave per 16-node tile) ----------
        const int lane = threadIdx.x & 63;
        const int m = lane & 15;
        const int q = lane >> 4;
        const int wv = threadIdx.x >> 6;
        const int wid0 = ((int)blockIdx.x - BB) * 8 + wv;
        const int nwaves = mm_blocks * 8;
        const int ntiles = (n_nodes + 15) >> 4;

        half8 bfrag[4][4];                       // W fragments hoisted once
#pragma unroll
        for (int kt = 0; kt < 4; ++kt) {
#pragma unroll
            for (int nt = 0; nt < 4; ++nt) {
                int k0 = kt * 32 + q * 8;
                int c = nt * 16 + m;
#pragma unroll
                for (int j = 0; j < 8; ++j)
                    bfrag[kt][nt][j] = (_Float16)W[(size_t)(k0 + j) * OUT_DIM + c];
            }
        }

        for (int wid = wid0; wid < ntiles; wid += nwaves) {
            const int nb = wid << 4;
            int arow = nb + m;
            if (arow >= n_nodes) arow = n_nodes - 1;
            const float* xr = x + (size_t)arow * IN_DIM;

            f32x4 acc[4];
#pragma unroll
            for (int nt = 0; nt < 4; ++nt) acc[nt] = (f32x4){0.f, 0.f, 0.f, 0.f};

#pragma unroll
            for (int kt = 0; kt < 4; ++kt) {
                const float4* xp = (const float4*)(xr + kt * 32 + q * 8);
                float4 lo = xp[0];
                float4 hi = xp[1];
                half8 afrag;
                afrag[0] = (_Float16)lo.x; afrag[1] = (_Float16)lo.y;
                afrag[2] = (_Float16)lo.z; afrag[3] = (_Float16)lo.w;
                afrag[4] = (_Float16)hi.x; afrag[5] = (_Float16)hi.y;
                afrag[6] = (_Float16)hi.z; afrag[7] = (_Float16)hi.w;
#pragma unroll
                for (int nt = 0; nt < 4; ++nt)
                    acc[nt] = __builtin_amdgcn_mfma_f32_16x16x32_f16(
                        afrag, bfrag[kt][nt], acc[nt], 0, 0, 0);
            }

#pragma unroll
            for (int r = 0; r < 4; ++r) {
                int node = nb + q * 4 + r;
                if (node < n_nodes) {
                    unsigned short* hp = h + (size_t)node * OUT_DIM + m;
#pragma unroll
                    for (int nt = 0; nt < 4; ++nt)
                        hp[nt * 16] = f2bf(acc[nt][r]);   // UNSCALED
                }
            }
        }
    }
}

// ---------------------------------------------------------------------------
// kD: per-bucket degree histogram from the 8 sub-slots (+spill filter).
// Writes dis AND the raw per-node counts cntg[bk][128] so kF can skip its
// own histogram pass.
// ---------------------------------------------------------------------------
__global__ void __launch_bounds__(256) kD_degree(
    const unsigned int* __restrict__ EdgeBuf, const int* __restrict__ BinSize,
    const uint2* __restrict__ spill, const int* __restrict__ spillcur,
    float* __restrict__ dis, int* __restrict__ cntg, int n_nodes, int nbf) {
    __shared__ int cnt[FNPB];
    int t = threadIdx.x;
    int b = blockIdx.x;
    if (t < FNPB) cnt[t] = 0;
    __syncthreads();
    for (int g = 0; g < NGRP; ++g) {
        int szg = min(BinSize[g * nbf + b], CAP_G);
        const unsigned int* sl = EdgeBuf + (size_t)b * CAP + g * CAP_G;
        for (int i = t; i < szg; i += 256)
            atomicAdd(&cnt[sl[i] & (FNPB - 1)], 1);
    }
    int sn = min(*spillcur, SPILL_MAX);          // usually 0
    for (int i = t; i < sn; i += 256) {
        uint2 e = spill[i];
        if ((int)(e.y >> FLOG) == b) atomicAdd(&cnt[e.y & (FNPB - 1)], 1);
    }
    __syncthreads();
    if (t < FNPB) {
        int d = cnt[t];
        cntg[(size_t)b * FNPB + t] = d;          // coalesced 512 B/block
        int node = (b << FLOG) + t;
        if (node < n_nodes)
            dis[node] = (d > 0) ? rsqrtf((float)d) : 0.0f;
    }
}

// ---------------------------------------------------------------------------
// kF: HALF-BUCKET sort+gather (round-12 measured form). 2*nbf blocks x 256
// threads, each owning 64 nodes; whole grid resident at once. Pinned at
// ~44.5us by the h-gather's L2/L3 random-access equilibrium (rounds 8/10/12:
// histogram-removal, MLP, residency all null).
// ---------------------------------------------------------------------------
__global__ void __launch_bounds__(KFT) kF_sortagg(
    const unsigned int* __restrict__ EdgeBuf, const int* __restrict__ BinSize,
    const uint2* __restrict__ spill, const int* __restrict__ spillcur,
    const unsigned short* __restrict__ h, const float* __restrict__ dis,
    const int* __restrict__ cntg, const float* __restrict__ b,
    float* __restrict__ out, int* __restrict__ arena, int* __restrict__ arenacur,
    int n_nodes, int nbf) {
    __shared__ int cnt[HALF];
    __shared__ int seg[HALF];
    __shared__ int cursor[HALF];
    __shared__ int sbuf[SBUF_CAP];
    __shared__ int abase_sh;
    int t = threadIdx.x;
    int bk = blockIdx.x >> 1;
    int halfid = blockIdx.x & 1;
    int lo = halfid * HALF;                      // node-local range [lo, lo+64)
    int nb0 = (bk << FLOG) + lo;
    int sn = min(*spillcur, SPILL_MAX);          // usually 0

    // wave-0 shfl scan over this half's 64 per-node counts
    if (t < 64) {
        int c = cntg[(size_t)bk * FNPB + lo + t];
        int s = c;
#pragma unroll
        for (int off = 1; off < 64; off <<= 1) {
            int y = __shfl_up(s, off, 64);
            if (t >= off) s += y;
        }
        cnt[t] = c;
        seg[t] = s;              // inclusive prefix
        cursor[t] = s - c;       // exclusive prefix
    }
    __syncthreads();

    int ne = seg[HALF - 1];
    if (t == 0 && ne > SBUF_CAP) abase_sh = atomicAdd(arenacur, ne);
    __syncthreads();

    const int lane = t & 63;
    const int wv = t >> 6;                       // 4 waves
    const int quarter = lane >> 4;
    const int qlane = lane & 15;
    float4 bias = ((const float4*)b)[qlane];

    if (ne <= SBUF_CAP) {
        for (int g = 0; g < NGRP; ++g) {
            int szg = min(BinSize[g * nbf + bk], CAP_G);
            const unsigned int* sl = EdgeBuf + (size_t)bk * CAP + g * CAP_G;
            for (int i = t; i < szg; i += KFT) {
                unsigned int v = sl[i];
                int nlocal = (int)(v & (FNPB - 1)) - lo;
                if ((unsigned)nlocal < HALF) {
                    int p = atomicAdd(&cursor[nlocal], 1);
                    sbuf[p] = (int)(v >> FLOG);
                }
            }
        }
        for (int i = t; i < sn; i += KFT) {
            uint2 e = spill[i];
            if ((int)(e.y >> FLOG) == bk) {
                int nlocal = (int)(e.y & (FNPB - 1)) - lo;
                if ((unsigned)nlocal < HALF) {
                    int p = atomicAdd(&cursor[nlocal], 1);
                    sbuf[p] = (int)e.x;
                }
            }
        }
        __syncthreads();

        for (int nl = wv; nl < HALF; nl += 4) {
            int node = nb0 + nl;
            if (node >= n_nodes) break;
            int e_ = seg[nl];
            int dcount = cnt[nl];
            int s_ = e_ - dcount;
            float a0 = 0.f, a1 = 0.f, a2 = 0.f, a3 = 0.f;
            for (int j0 = s_; j0 < e_; j0 += 16) {
                int i0 = j0 + quarter;
                int i1 = i0 + 4;
                int i2 = i0 + 8;
                int i3 = i0 + 12;
                int r0 = sbuf[i0 < e_ ? i0 : s_];
                int r1 = sbuf[i1 < e_ ? i1 : s_];
                int r2 = sbuf[i2 < e_ ? i2 : s_];
                int r3 = sbuf[i3 < e_ ? i3 : s_];
                float d0 = dis[r0];
                float d1 = dis[r1];
                float d2 = dis[r2];
                float d3 = dis[r3];
                uint2 v0 = make_uint2(0u, 0u), v1 = v0, v2 = v0, v3 = v0;
                if (i0 < e_)
                    v0 = *(const uint2*)(h + (size_t)r0 * OUT_DIM + qlane * 4);
                if (i1 < e_)
                    v1 = *(const uint2*)(h + (size_t)r1 * OUT_DIM + qlane * 4);
                if (i2 < e_)
                    v2 = *(const uint2*)(h + (size_t)r2 * OUT_DIM + qlane * 4);
                if (i3 < e_)
                    v3 = *(const uint2*)(h + (size_t)r3 * OUT_DIM + qlane * 4);
                a0 = fmaf(__uint_as_float(v0.x << 16), d0, a0);
                a1 = fmaf(__uint_as_float(v0.x & 0xFFFF0000u), d0, a1);
                a2 = fmaf(__uint_as_float(v0.y << 16), d0, a2);
                a3 = fmaf(__uint_as_float(v0.y & 0xFFFF0000u), d0, a3);
                a0 = fmaf(__uint_as_float(v1.x << 16), d1, a0);
                a1 = fmaf(__uint_as_float(v1.x & 0xFFFF0000u), d1, a1);
                a2 = fmaf(__uint_as_float(v1.y << 16), d1, a2);
                a3 = fmaf(__uint_as_float(v1.y & 0xFFFF0000u), d1, a3);
                a0 = fmaf(__uint_as_float(v2.x << 16), d2, a0);
                a1 = fmaf(__uint_as_float(v2.x & 0xFFFF0000u), d2, a1);
                a2 = fmaf(__uint_as_float(v2.y << 16), d2, a2);
                a3 = fmaf(__uint_as_float(v2.y & 0xFFFF0000u), d2, a3);
                a0 = fmaf(__uint_as_float(v3.x << 16), d3, a0);
                a1 = fmaf(__uint_as_float(v3.x & 0xFFFF0000u), d3, a1);
                a2 = fmaf(__uint_as_float(v3.y << 16), d3, a2);
                a3 = fmaf(__uint_as_float(v3.y & 0xFFFF0000u), d3, a3);
            }
            a0 += __shfl_xor(a0, 16, 64); a0 += __shfl_xor(a0, 32, 64);
            a1 += __shfl_xor(a1, 16, 64); a1 += __shfl_xor(a1, 32, 64);
            a2 += __shfl_xor(a2, 16, 64); a2 += __shfl_xor(a2, 32, 64);
            a3 += __shfl_xor(a3, 16, 64); a3 += __shfl_xor(a3, 32, 64);
            if (quarter == 0) {
                float dv = (dcount > 0) ? rsqrtf((float)dcount) : 0.0f;
                float4 o;
                o.x = fmaxf(fmaf(a0, dv, bias.x), 0.f);
                o.y = fmaxf(fmaf(a1, dv, bias.y), 0.f);
                o.z = fmaxf(fmaf(a2, dv, bias.z), 0.f);
                o.w = fmaxf(fmaf(a3, dv, bias.w), 0.f);
                ((float4*)(out + (size_t)node * OUT_DIM))[qlane] = o;
            }
        }
    } else {
        // impossible-size half-bucket: sort into a global arena slice
        int abase = abase_sh;
        for (int g = 0; g < NGRP; ++g) {
            int szg = min(BinSize[g * nbf + bk], CAP_G);
            const unsigned int* sl = EdgeBuf + (size_t)bk * CAP + g * CAP_G;
            for (int i = t; i < szg; i += KFT) {
                unsigned int v = sl[i];
                int nlocal = (int)(v & (FNPB - 1)) - lo;
                if ((unsigned)nlocal < HALF) {
                    int p = atomicAdd(&cursor[nlocal], 1);
                    arena[abase + p] = (int)(v >> FLOG);
                }
            }
        }
        for (int i = t; i < sn; i += KFT) {
            uint2 e = spill[i];
            if ((int)(e.y >> FLOG) == bk) {
                int nlocal = (int)(e.y & (FNPB - 1)) - lo;
                if ((unsigned)nlocal < HALF) {
                    int p = atomicAdd(&cursor[nlocal], 1);
                    arena[abase + p] = (int)e.x;
                }
            }
        }
        __threadfence();
        __syncthreads();
        for (int nl = wv; nl < HALF; nl += 4) {
            int node = nb0 + nl;
            if (node >= n_nodes) break;
            int e_ = seg[nl];
            int dcount = cnt[nl];
            int s_ = e_ - dcount;
            float a0 = 0.f, a1 = 0.f, a2 = 0.f, a3 = 0.f;
            for (int j0 = s_; j0 < e_; j0 += 8) {
                int iA = j0 + quarter;
                int iB = j0 + quarter + 4;
                int rA = arena[abase + (iA < e_ ? iA : s_)];
                int rB = arena[abase + (iB < e_ ? iB : s_)];
                float dA = dis[rA];
                float dB = dis[rB];
                uint2 vA = make_uint2(0u, 0u), vB = make_uint2(0u, 0u);
                if (iA < e_)
                    vA = *(const uint2*)(h + (size_t)rA * OUT_DIM + qlane * 4);
                if (iB < e_)
                    vB = *(const uint2*)(h + (size_t)rB * OUT_DIM + qlane * 4);
                a0 = fmaf(__uint_as_float(vA.x << 16), dA, a0);
                a1 = fmaf(__uint_as_float(vA.x & 0xFFFF0000u), dA, a1);
                a2 = fmaf(__uint_as_float(vA.y << 16), dA, a2);
                a3 = fmaf(__uint_as_float(vA.y & 0xFFFF0000u), dA, a3);
                a0 = fmaf(__uint_as_float(vB.x << 16), dB, a0);
                a1 = fmaf(__uint_as_float(vB.x & 0xFFFF0000u), dB, a1);
                a2 = fmaf(__uint_as_float(vB.y << 16), dB, a2);
                a3 = fmaf(__uint_as_float(vB.y & 0xFFFF0000u), dB, a3);
            }
            a0 += __shfl_xor(a0, 16, 64); a0 += __shfl_xor(a0, 32, 64);
            a1 += __shfl_xor(a1, 16, 64); a1 += __shfl_xor(a1, 32, 64);
            a2 += __shfl_xor(a2, 16, 64); a2 += __shfl_xor(a2, 32, 64);
            a3 += __shfl_xor(a3, 16, 64); a3 += __shfl_xor(a3, 32, 64);
            if (quarter == 0) {
                float dv = (dcount > 0) ? rsqrtf((float)dcount) : 0.0f;
                float4 o;
                o.x = fmaxf(fmaf(a0, dv, bias.x), 0.f);
                o.y = fmaxf(fmaf(a1, dv, bias.y), 0.f);
                o.z = fmaxf(fmaf(a2, dv, bias.z), 0.f);
                o.w = fmaxf(fmaf(a3, dv, bias.w), 0.f);
                ((float4*)(out + (size_t)node * OUT_DIM))[qlane] = o;
            }
        }
    }
}

// ---------------------------------------------------------------------------
// Last-resort fallback (exotic sizes): atomic scatter, fp32 h
// ---------------------------------------------------------------------------
#define MM_NODES 16
__global__ void __launch_bounds__(256) k_matmul_f32(
    const float* __restrict__ x, const float* __restrict__ W,
    const float* __restrict__ dis, float* __restrict__ h, int n_nodes) {
    __shared__ float xs[MM_NODES * IN_DIM];
    const int lane = threadIdx.x & 63;
    const int wv = threadIdx.x >> 6;
    float w[IN_DIM];
#pragma unroll
    for (int k = 0; k < IN_DIM; ++k) w[k] = W[k * OUT_DIM + lane];
    int nchunks = (n_nodes + MM_NODES - 1) / MM_NODES;
    for (int ch = blockIdx.x; ch < nchunks; ch += gridDim.x) {
        int base = ch * MM_NODES;
        int nrows = min(MM_NODES, n_nodes - base);
        __syncthreads();
        const float4* xg = (const float4*)(x + (size_t)base * IN_DIM);
        int nf4 = nrows * IN_DIM / 4;
        for (int i = threadIdx.x; i < nf4; i += 256) ((float4*)xs)[i] = xg[i];
        __syncthreads();
#pragma unroll
        for (int j = 0; j < 4; ++j) {
            int local = wv * 4 + j;
            int node = base + local;
            if (local < nrows) {
                const float4* xr = (const float4*)(xs + local * IN_DIM);
                float acc = 0.0f;
#pragma unroll
                for (int k4 = 0; k4 < IN_DIM / 4; ++k4) {
                    float4 xv = xr[k4];
                    acc = fmaf(xv.x, w[k4 * 4 + 0], acc);
                    acc = fmaf(xv.y, w[k4 * 4 + 1], acc);
                    acc = fmaf(xv.z, w[k4 * 4 + 2], acc);
                    acc = fmaf(xv.w, w[k4 * 4 + 3], acc);
                }
                h[(size_t)node * OUT_DIM + lane] = acc * dis[node];
            }
        }
    }
}

__global__ void k_degree_fb(const int* __restrict__ col, int* __restrict__ deg,
                            int n_edges) {
    int i = blockIdx.x * blockDim.x + threadIdx.x;
    int stride = gridDim.x * blockDim.x;
    for (; i < n_edges; i += stride) atomicAdd(&deg[col[i]], 1);
}

__global__ void k_rsqrt_fb(const int* __restrict__ deg, float* __restrict__ dis, int n) {
    int i = blockIdx.x * blockDim.x + threadIdx.x;
    if (i < n) {
        int d = deg[i];
        dis[i] = (d > 0) ? rsqrtf((float)d) : 0.0f;
    }
}

__global__ void __launch_bounds__(256) k_scatter_fb(
    const int* __restrict__ row, const int* __restrict__ col,
    const float* __restrict__ dis, const float* __restrict__ h,
    float* __restrict__ out, int n_edges) {
    const int lane = threadIdx.x & 63;
    int e = (blockIdx.x * blockDim.x + threadIdx.x) >> 6;
    int nw = (gridDim.x * blockDim.x) >> 6;
    for (; e < n_edges; e += nw) {
        int r = row[e];
        int c = col[e];
        float v = h[(size_t)r * OUT_DIM + lane] * dis[c];
        atomicAdd(&out[(size_t)c * OUT_DIM + lane], v);
    }
}

__global__ void k_bias_relu_fb(float* __restrict__ out, const float* __restrict__ b,
                               int total) {
    int i = blockIdx.x * blockDim.x + threadIdx.x;
    int stride = gridDim.x * blockDim.x;
    for (; i < total; i += stride) {
        float v = out[i] + b[i & (OUT_DIM - 1)];
        out[i] = fmaxf(v, 0.0f);
    }
}

extern "C" void kernel_launch(void* const* d_in, const int* in_sizes, int n_in,
                              void* d_out, int out_size, void* d_ws, size_t ws_size,
                              hipStream_t stream) {
    const float* x = (const float*)d_in[0];
    const int* ei = (const int*)d_in[1];  // [2, E] int32
    const float* W = (const float*)d_in[2];
    const float* b = (const float*)d_in[3];
    float* out = (float*)d_out;

    const int n_nodes = in_sizes[0] / IN_DIM;
    const int n_edges = in_sizes[1] / 2;
    const int* row = ei;
    const int* col = ei + n_edges;

    const int nbf = (n_nodes + FNPB - 1) >> FLOG;   // fine buckets
    const int chunk = (n_edges + BB - 1) / BB;

    // ---- workspace layout (BinSize[8][nbf] + cursors contiguous: one memset) ----
    char* wsb = (char*)d_ws;
    size_t off = 0;
    int* BinSize = (int*)(wsb + off);    off += (size_t)(nbf * NGRP + 8) * 4;
    int* spillcur = BinSize + nbf * NGRP;
    int* arenacur = BinSize + nbf * NGRP + 1;
    const size_t zero_bytes = off;
    off = align_up(off, 256);
    unsigned int* EdgeBuf = (unsigned int*)(wsb + off);
                                         off += align_up((size_t)nbf * CAP * 4, 256);
    uint2* spill = (uint2*)(wsb + off);  off += align_up((size_t)SPILL_MAX * 8, 256);
    int* arena = (int*)(wsb + off);      off += align_up((size_t)n_edges * 4, 256);
    float* dis = (float*)(wsb + off);    off += align_up((size_t)n_nodes * 4, 256);
    int* cntg = (int*)(wsb + off);       off += align_up((size_t)nbf * FNPB * 4, 256);
    unsigned short* h = (unsigned short*)(wsb + off);
                                         off += (size_t)n_nodes * OUT_DIM * 2;
    const size_t needed = off;

    const bool ok = (ws_size >= needed) && (nbf <= MAXFINE) &&
                    (chunk <= MAXE * BT) && (n_nodes <= (1 << 24));

    if (ok) {
        const int ntiles = (n_nodes + 15) >> 4;
        int mm_blocks = (ntiles + 15) / 16;          // 8 waves/block, 2 tiles/wave
        if (mm_blocks < 1) mm_blocks = 1;
        hipMemsetAsync(BinSize, 0, zero_bytes, stream);
        k_build_mm<<<BB + mm_blocks, BT, 0, stream>>>(
            row, col, BinSize, EdgeBuf, spill, spillcur,
            x, W, h, n_edges, n_nodes, nbf, chunk, mm_blocks);
        kD_degree<<<nbf, 256, 0, stream>>>(EdgeBuf, BinSize, spill, spillcur,
                                           dis, cntg, n_nodes, nbf);
        kF_sortagg<<<2 * nbf, KFT, 0, stream>>>(EdgeBuf, BinSize, spill, spillcur,
                                                h, dis, cntg, b, out, arena,
                                                arenacur, n_nodes, nbf);
    } else {
        // ---- last-resort fallback: atomic scatter, fp32 h ----
        char* p = (char*)d_ws;
        int* deg_f = (int*)p;
        float* dis_f = (float*)(p + align_up((size_t)n_nodes * 4, 256));
        float* h_f = (float*)(p + 2 * align_up((size_t)n_nodes * 4, 256));
        hipMemsetAsync(deg_f, 0, (size_t)n_nodes * 4, stream);
        hipMemsetAsync(out, 0, (size_t)out_size * 4, stream);
        k_degree_fb<<<1024, 256, 0, stream>>>(col, deg_f, n_edges);
        k_rsqrt_fb<<<(n_nodes + 255) / 256, 256, 0, stream>>>(deg_f, dis_f, n_nodes);
        k_matmul_f32<<<1024, 256, 0, stream>>>(x, W, dis_f, h_f, n_nodes);
        k_scatter_fb<<<2048, 256, 0, stream>>>(row, col, dis_f, h_f, out, n_edges);
        k_bias_relu_fb<<<2048, 256, 0, stream>>>(out, b, n_nodes * OUT_DIM);
    }
}